// Round 16
// baseline (63.020 us; speedup 1.0000x reference)
//
#include <hip/hip_runtime.h>
#include <hip/hip_bf16.h>

#define BB 8
#define SS 256
#define CHAR_E 128
#define BI_E 64
#define EMBED 256
#define HH 256
#define NTAGS 17
#define SPAD 260   // S + 2 zero-pad rows each side
#define NROWS 2048 // B*S
#define NLOG2E -1.4426950408889634f

typedef __attribute__((ext_vector_type(8))) short short8;
typedef __attribute__((ext_vector_type(4))) float f32x4;
typedef __attribute__((ext_vector_type(2))) float f32x2;
#define MFMA16(a, b, c) __builtin_amdgcn_mfma_f32_16x16x32_bf16(a, b, c, 0, 0, 0)

__device__ __forceinline__ float fast_rcp(float x) {
    return __builtin_amdgcn_rcpf(x);
}
__device__ __forceinline__ float fast_exp2(float x) {
    return __builtin_amdgcn_exp2f(x);
}
__device__ __forceinline__ float fast_tanh(float x) {
    float e = __expf(2.0f * x);
    return 1.0f - 2.0f * fast_rcp(e + 1.0f);
}

// ---- fused: embed gather -> xbf; pack WcombT/W01T; lengths -----------------
__global__ __launch_bounds__(256) void embed_pack_kernel(
        const int* __restrict__ tokens,
        const float* __restrict__ char_emb,
        const float* __restrict__ bigram_emb,
        const float* __restrict__ w1, const float* __restrict__ w3,
        const float* __restrict__ w5,
        const float* __restrict__ W0, const float* __restrict__ W1mat,
        const int* __restrict__ masks,
        __hip_bfloat16* __restrict__ xbf,
        __hip_bfloat16* __restrict__ WcombT,
        __hip_bfloat16* __restrict__ W01T,
        float* __restrict__ Linv_buf) {
    int blk = blockIdx.x;
    int t = threadIdx.x;
    if (blk < BB * SPAD) {
        int b = blk / SPAD, r = blk % SPAD;
        float v = 0.0f;
        if (r >= 2 && r < SS + 2) {
            int s = r - 2;
            const int* tk = tokens + (b * SS + s) * 3;
            if (t < CHAR_E)              v = char_emb[tk[0] * CHAR_E + t];
            else if (t < CHAR_E + BI_E)  v = bigram_emb[tk[1] * BI_E + (t - CHAR_E)];
            else                         v = bigram_emb[tk[2] * BI_E + (t - CHAR_E - BI_E)];
        }
        xbf[blk * EMBED + t] = __float2bfloat16(v);
    } else if (blk < BB * SPAD + 160) {
        // WcombT pack: block = 8 kk-cols, thread = h; short8 (16B) stores
        int kk0 = (blk - BB * SPAD) * 8;
        int h = t, hc = h >> 4, hl = h & 15;
        union { short8 v; __hip_bfloat16 b[8]; } u5, u3, u1;
        #pragma unroll
        for (int k = 0; k < 8; ++k) {
            int kk = kk0 + k, tap = kk >> 8, e = kk & 255;
            float f5 = w5[(tap * EMBED + e) * HH + h];
            float f3 = (tap >= 1 && tap <= 3) ? w3[((tap - 1) * EMBED + e) * HH + h] : 0.f;
            float f1 = (tap == 2) ? w1[e * HH + h] : 0.f;
            u5.b[k] = __float2bfloat16(f5);
            u3.b[k] = __float2bfloat16(f3);
            u1.b[k] = __float2bfloat16(f1);
        }
        *(short8*)(WcombT + (hc * 48 +  0 + hl) * 1280 + kk0) = u5.v;
        *(short8*)(WcombT + (hc * 48 + 16 + hl) * 1280 + kk0) = u3.v;
        *(short8*)(WcombT + (hc * 48 + 32 + hl) * 1280 + kk0) = u1.v;
    } else if (blk < BB * SPAD + 160 + 256) {
        // W01T pack: block = e, threads = h (reads coalesced over h)
        int e = blk - BB * SPAD - 160;
        W01T[t * 256 + e]         = __float2bfloat16(W0[e * HH + t]);
        W01T[(256 + t) * 256 + e] = __float2bfloat16(W1mat[e * HH + t]);
    } else {
        // lengths: b = t>>5, 32 lanes each sum 8 masks, shuffle-reduce
        int b = t >> 5, l = t & 31;
        int ssum = 0;
        #pragma unroll
        for (int k = 0; k < 8; ++k) ssum += masks[b * SS + l * 8 + k];
        #pragma unroll
        for (int o = 16; o; o >>= 1) ssum += __shfl_xor(ssum, o);
        if (l == 0) Linv_buf[b] = (ssum > 0) ? (1.0f / (float)ssum) : 0.0f;
    }
}

// ---- conv as LDS-tiled MFMA GEMM (BM=64, BN=48, BK=128, dbuf) --------------
// XCD-swizzled block ids: each XCD owns 4 mt's (A-panels stay L2-local).
// Epilogue: tanh+max -> cbf[row][h] (bf16) and cmT[h][row] = c*m*Linv (f32).
__global__ __launch_bounds__(256, 2) void conv_mfma_fused(
        const __hip_bfloat16* __restrict__ xbf,
        const __hip_bfloat16* __restrict__ WcombT,
        const float* __restrict__ cb1, const float* __restrict__ cb3,
        const float* __restrict__ cb5,
        const int* __restrict__ masks, const float* __restrict__ Linv_buf,
        __hip_bfloat16* __restrict__ cbf, float* __restrict__ cmT) {
    __shared__ short8 sA[2][1024];   // [64 rows][16 chunks], 16KB per buf
    __shared__ short8 sB[2][768];    // [48 rows][16 chunks], 12KB per buf

    int blk = blockIdx.x;            // XCD swizzle: xcd=blk&7 owns mts xcd*4..+3
    int slot = blk >> 3;
    int mt = (blk & 7) * 4 + (slot >> 4);
    int hc = slot & 15;
    int tid = threadIdx.x, w = tid >> 6, lane = tid & 63;
    int fr = lane & 15, fq = lane >> 4;
    int row0 = mt * 64;
    int b = row0 >> 8, s0 = row0 & 255;
    const __hip_bfloat16* xbase = xbf + (b * SPAD + s0) * EMBED;
    const __hip_bfloat16* wbase = WcombT + (hc * 48) * 1280;

    short8 va[4], vb[3];
    auto LOADG = [&](int q) {
        int tap = q >> 1, e0 = (q & 1) * 128;
        const __hip_bfloat16* xs = xbase + tap * EMBED + e0;
        #pragma unroll
        for (int it = 0; it < 4; ++it) {
            int s = tid + it * 256, r = s >> 4, cg = s & 15;
            va[it] = *(const short8*)(xs + r * EMBED + cg * 8);
        }
        const __hip_bfloat16* wsrc = wbase + q * 128;
        #pragma unroll
        for (int it = 0; it < 3; ++it) {
            int s = tid + it * 256, r = s >> 4, cg = s & 15;
            vb[it] = *(const short8*)(wsrc + r * 1280 + cg * 8);
        }
    };
    auto WRITE = [&](int buf) {
        #pragma unroll
        for (int it = 0; it < 4; ++it) {
            int s = tid + it * 256, r = s >> 4, cg = s & 15;
            sA[buf][r * 16 + (cg ^ (r & 15))] = va[it];
        }
        #pragma unroll
        for (int it = 0; it < 3; ++it) {
            int s = tid + it * 256, r = s >> 4, cg = s & 15;
            sB[buf][r * 16 + (cg ^ (r & 15))] = vb[it];
        }
    };

    LOADG(0);
    WRITE(0);
    __syncthreads();

    f32x4 acc0 = {}, acc1 = {}, acc2 = {};
    int ra = w * 16 + fr;            // wave w owns rows w*16..+15
    int cur = 0;
    for (int q = 0; q < 10; ++q) {
        if (q < 9) LOADG(q + 1);
        #pragma unroll
        for (int ks = 0; ks < 4; ++ks) {
            int c = ks * 4 + fq;
            short8 a  = sA[cur][ra * 16 + (c ^ (ra & 15))];
            short8 q0 = sB[cur][fr * 16        + (c ^ fr)];
            short8 q1 = sB[cur][(16 + fr) * 16 + (c ^ fr)];
            short8 q2 = sB[cur][(32 + fr) * 16 + (c ^ fr)];
            acc0 = MFMA16(a, q0, acc0);
            acc1 = MFMA16(a, q1, acc1);
            acc2 = MFMA16(a, q2, acc2);
        }
        if (q < 9) WRITE(cur ^ 1);
        __syncthreads();
        cur ^= 1;
    }

    int h = hc * 16 + fr;
    float bb5 = cb5[h], bb3 = cb3[h], bb1 = cb1[h];
    float Linv = Linv_buf[b];
    #pragma unroll
    for (int j = 0; j < 4; ++j) {
        int row = row0 + w * 16 + fq * 4 + j;
        float t5 = fast_tanh(acc0[j] + bb5);
        float t3 = fast_tanh(acc1[j] + bb3);
        float t1 = fast_tanh(acc2[j] + bb1);
        float v = fmaxf(t1, fmaxf(t3, t5));
        cbf[row * HH + h] = __float2bfloat16(v);
        cmT[h * NROWS + row] = v * (float)masks[row] * Linv;
    }
}

// ---- g0/g1 GEMM; full register prefetch; E=exp2(-log2e*(v+bias)) -----------
// Outputs TRANSPOSED [h][row] via LDS transpose (coalesced 32B stores).
__global__ __launch_bounds__(256) void gemm_g_mfma_kernel(
        const __hip_bfloat16* __restrict__ cbf,
        const __hip_bfloat16* __restrict__ W01T,
        const float* __restrict__ b0, const float* __restrict__ b1v,
        float* __restrict__ E0T, float* __restrict__ E1T) {
    __shared__ float s_out[64][33];  // [colLocal][rowLocal], padded

    int blk = blockIdx.x;            // 64 m-tiles * 8 n-tiles = 512
    int by = blk >> 3, bx = blk & 7;
    int tid = threadIdx.x;
    int w = tid >> 6, lane = tid & 63;
    int wr = w >> 1, wc = w & 1;
    int m0 = by * 32 + wr * 16;
    int n0 = bx * 64 + wc * 32;
    int fr = lane & 15, fq = lane >> 4;

    const short8* ap  = (const short8*)(cbf + (m0 + fr) * HH + fq * 8);
    const short8* bp0 = (const short8*)(W01T + (n0 + fr) * HH + fq * 8);
    const short8* bp1 = (const short8*)(W01T + (n0 + 16 + fr) * HH + fq * 8);

    short8 af[8], bf0[8], bf1[8];    // all 24 loads issued up front
    #pragma unroll
    for (int ks = 0; ks < 8; ++ks) af[ks] = ap[ks * 4];
    #pragma unroll
    for (int ks = 0; ks < 8; ++ks) { bf0[ks] = bp0[ks * 4]; bf1[ks] = bp1[ks * 4]; }

    f32x4 acc[2] = {};
    #pragma unroll
    for (int ks = 0; ks < 8; ++ks) {
        acc[0] = MFMA16(af[ks], bf0[ks], acc[0]);
        acc[1] = MFMA16(af[ks], bf1[ks], acc[1]);
    }
    #pragma unroll
    for (int n = 0; n < 2; ++n) {
        int col = n0 + n * 16 + fr;
        float bias = (col < 256) ? b0[col] : b1v[col - 256];
        int cl = wc * 32 + n * 16 + fr;
        #pragma unroll
        for (int j = 0; j < 4; ++j) {
            int rl = wr * 16 + fq * 4 + j;
            s_out[cl][rl] = fast_exp2(NLOG2E * (acc[n][j] + bias));
        }
    }
    __syncthreads();
    {
        float* dstbase = (bx < 4) ? (E0T + (bx * 64) * NROWS)
                                  : (E1T + (bx * 64 - 256) * NROWS);
        int cl = tid >> 2, rq = tid & 3;   // 64 cols x 4 row-octets
        f32x4 o0, o1;
        #pragma unroll
        for (int k = 0; k < 4; ++k) { o0[k] = s_out[cl][rq * 8 + k];
                                      o1[k] = s_out[cl][rq * 8 + 4 + k]; }
        float* dst = dstbase + cl * NROWS + by * 32 + rq * 8;
        *(f32x4*)dst = o0;
        *(f32x4*)(dst + 4) = o1;
    }
}

// ---- relation: block=(b,h); threads=i; per-j operands via SCALAR loads -----
// {E1T[h][j], cmT[h][j]} are block-uniform -> s_load batches; inner loop is
// pure fma/rcp/fma with SGPR operands. No LDS, no barrier.
__global__ __launch_bounds__(256) void relation_kernel(
        const float* __restrict__ E0T, const float* __restrict__ E1T,
        const float* __restrict__ cmT, const int* __restrict__ masks,
        float* __restrict__ relT) {
    int blk = blockIdx.x;            // b*256 + h
    int b = blk >> 8, h = blk & 255;
    int i = threadIdx.x;
    int row = b * SS + i;

    const float* e1p = E1T + h * NROWS + b * SS;   // uniform base
    const float* cmp = cmT + h * NROWS + b * SS;   // uniform base

    float e0 = E0T[h * NROWS + row];               // coalesced vector load
    float acc = 0.f;
    #pragma unroll 8
    for (int j = 0; j < SS; ++j) {
        float e1 = e1p[j];                         // uniform -> s_load
        float cm = cmp[j];                         // uniform -> s_load
        acc = fmaf(fast_rcp(fmaf(e0, e1, 1.0f)), cm, acc);
    }
    float mi = (float)masks[row];
    relT[h * NROWS + row] = fast_tanh(acc * mi);   // coalesced
}

// ---- final: coalesced relT reads, Wo in LDS, partial-reduce, softmax -------
// block = (b, 32 i's); threads = 8 h-groups x 32 i.
__global__ __launch_bounds__(256) void final_kernel(
        const float* __restrict__ relT,
        const float* __restrict__ Wo, const float* __restrict__ bo,
        float* __restrict__ out) {
    int blk = blockIdx.x;            // b*8 + iblk
    int b = blk >> 3, iblk = blk & 7;
    int tid = threadIdx.x;
    int hg = tid >> 5, il = tid & 31;
    int row = b * SS + iblk * 32 + il;

    __shared__ float wo_s[HH * NTAGS];       // 17.0 KB
    __shared__ float part[8][32][NTAGS];     // 17.4 KB

    for (int idx = tid; idx < HH * NTAGS; idx += 256) wo_s[idx] = Wo[idx];
    __syncthreads();

    float acc[NTAGS];
    #pragma unroll
    for (int t = 0; t < NTAGS; ++t) acc[t] = 0.f;
    const float* rbase = relT + row;
    for (int k = 0; k < 32; ++k) {
        int hh = hg * 32 + k;
        float v = rbase[hh * NROWS];         // 128B coalesced per 32 lanes
        const float* wrow = wo_s + hh * NTAGS;
        #pragma unroll
        for (int t = 0; t < NTAGS; ++t) acc[t] = fmaf(v, wrow[t], acc[t]);
    }
    #pragma unroll
    for (int t = 0; t < NTAGS; ++t) part[hg][il][t] = acc[t];
    __syncthreads();

    for (int idx = tid; idx < 32 * NTAGS; idx += 256) {
        int ii = idx / NTAGS, t = idx - ii * NTAGS;
        float s = bo[t];
        #pragma unroll
        for (int g = 0; g < 8; ++g) s += part[g][ii][t];
        part[0][ii][t] = s;
    }
    __syncthreads();

    if (tid < 32) {
        float mx = -1e30f;
        #pragma unroll
        for (int t = 0; t < NTAGS; ++t) mx = fmaxf(mx, part[0][tid][t]);
        float ex[NTAGS], sum = 0.f;
        #pragma unroll
        for (int t = 0; t < NTAGS; ++t) { ex[t] = __expf(part[0][tid][t] - mx); sum += ex[t]; }
        float si = fast_rcp(sum);
        int orow = b * SS + iblk * 32 + tid;
        #pragma unroll
        for (int t = 0; t < NTAGS; ++t)
            out[orow * NTAGS + t] = ex[t] * si;
    }
}

extern "C" void kernel_launch(void* const* d_in, const int* in_sizes, int n_in,
                              void* d_out, int out_size, void* d_ws, size_t ws_size,
                              hipStream_t stream) {
    const int*   tokens     = (const int*)d_in[0];
    const int*   masks      = (const int*)d_in[1];
    const float* char_emb   = (const float*)d_in[2];
    const float* bigram_emb = (const float*)d_in[3];
    const float* conv1_w    = (const float*)d_in[4];
    const float* conv1_b    = (const float*)d_in[5];
    const float* conv3_w    = (const float*)d_in[6];
    const float* conv3_b    = (const float*)d_in[7];
    const float* conv5_w    = (const float*)d_in[8];
    const float* conv5_b    = (const float*)d_in[9];
    const float* W0         = (const float*)d_in[10];
    const float* b0         = (const float*)d_in[11];
    const float* W1         = (const float*)d_in[12];
    const float* b1         = (const float*)d_in[13];
    const float* Wo         = (const float*)d_in[14];
    const float* bo         = (const float*)d_in[15];
    float* out = (float*)d_out;

    char* p = (char*)d_ws;
    __hip_bfloat16* xbf    = (__hip_bfloat16*)p;  p += BB * SPAD * EMBED * 2;   // 1.06 MB
    __hip_bfloat16* WcombT = (__hip_bfloat16*)p;  p += 768 * 1280 * 2;          // 1.97 MB
    __hip_bfloat16* W01T   = (__hip_bfloat16*)p;  p += 512 * 256 * 2;           // 0.26 MB
    __hip_bfloat16* cbf    = (__hip_bfloat16*)p;  p += NROWS * HH * 2;          // 1.05 MB
    float* cmT  = (float*)p;  p += (size_t)HH * NROWS * 4;                      // 2.1 MB
    float* E0T  = (float*)p;  p += (size_t)HH * NROWS * 4;                      // 2.1 MB
    float* E1T  = (float*)p;  p += (size_t)HH * NROWS * 4;                      // 2.1 MB
    float* relT = (float*)p;  p += (size_t)HH * NROWS * 4;                      // 2.1 MB
    float* Linv_buf = (float*)p;  p += 64;

    embed_pack_kernel<<<BB * SPAD + 160 + 256 + 1, 256, 0, stream>>>(
        tokens, char_emb, bigram_emb, conv1_w, conv3_w, conv5_w, W0, W1,
        masks, xbf, WcombT, W01T, Linv_buf);
    conv_mfma_fused<<<512, 256, 0, stream>>>(xbf, WcombT, conv1_b, conv3_b,
                                             conv5_b, masks, Linv_buf, cbf, cmT);
    gemm_g_mfma_kernel<<<512, 256, 0, stream>>>(cbf, W01T, b0, b1, E0T, E1T);
    relation_kernel<<<BB * 256, 256, 0, stream>>>(E0T, E1T, cmT, masks, relT);
    final_kernel<<<BB * 8, 256, 0, stream>>>(relT, Wo, bo, out);
}

// Round 17
// 61.063 us; speedup vs baseline: 1.0320x; 1.0320x over previous
//
#include <hip/hip_runtime.h>
#include <hip/hip_bf16.h>

#define BB 8
#define SS 256
#define CHAR_E 128
#define BI_E 64
#define EMBED 256
#define HH 256
#define NTAGS 17
#define SPAD 260   // S + 2 zero-pad rows each side
#define NROWS 2048 // B*S
#define NLOG2E -1.4426950408889634f

typedef __attribute__((ext_vector_type(8))) short short8;
typedef __attribute__((ext_vector_type(4))) float f32x4;
typedef __attribute__((ext_vector_type(2))) float f32x2;
#define MFMA16(a, b, c) __builtin_amdgcn_mfma_f32_16x16x32_bf16(a, b, c, 0, 0, 0)

__device__ __forceinline__ float fast_rcp(float x) {
    return __builtin_amdgcn_rcpf(x);
}
__device__ __forceinline__ float fast_exp2(float x) {
    return __builtin_amdgcn_exp2f(x);
}
__device__ __forceinline__ float fast_tanh(float x) {
    float e = __expf(2.0f * x);
    return 1.0f - 2.0f * fast_rcp(e + 1.0f);
}

// ---- fused: embed gather -> xbf; pack WcombT/W01T; lengths -----------------
__global__ __launch_bounds__(256) void embed_pack_kernel(
        const int* __restrict__ tokens,
        const float* __restrict__ char_emb,
        const float* __restrict__ bigram_emb,
        const float* __restrict__ w1, const float* __restrict__ w3,
        const float* __restrict__ w5,
        const float* __restrict__ W0, const float* __restrict__ W1mat,
        const int* __restrict__ masks,
        __hip_bfloat16* __restrict__ xbf,
        __hip_bfloat16* __restrict__ WcombT,
        __hip_bfloat16* __restrict__ W01T,
        float* __restrict__ Linv_buf) {
    int blk = blockIdx.x;
    int t = threadIdx.x;
    if (blk < BB * SPAD) {
        int b = blk / SPAD, r = blk % SPAD;
        float v = 0.0f;
        if (r >= 2 && r < SS + 2) {
            int s = r - 2;
            const int* tk = tokens + (b * SS + s) * 3;
            if (t < CHAR_E)              v = char_emb[tk[0] * CHAR_E + t];
            else if (t < CHAR_E + BI_E)  v = bigram_emb[tk[1] * BI_E + (t - CHAR_E)];
            else                         v = bigram_emb[tk[2] * BI_E + (t - CHAR_E - BI_E)];
        }
        xbf[blk * EMBED + t] = __float2bfloat16(v);
    } else if (blk < BB * SPAD + 160) {
        // WcombT pack: block = 8 kk-cols, thread = h; short8 (16B) stores
        int kk0 = (blk - BB * SPAD) * 8;
        int h = t, hc = h >> 4, hl = h & 15;
        union { short8 v; __hip_bfloat16 b[8]; } u5, u3, u1;
        #pragma unroll
        for (int k = 0; k < 8; ++k) {
            int kk = kk0 + k, tap = kk >> 8, e = kk & 255;
            float f5 = w5[(tap * EMBED + e) * HH + h];
            float f3 = (tap >= 1 && tap <= 3) ? w3[((tap - 1) * EMBED + e) * HH + h] : 0.f;
            float f1 = (tap == 2) ? w1[e * HH + h] : 0.f;
            u5.b[k] = __float2bfloat16(f5);
            u3.b[k] = __float2bfloat16(f3);
            u1.b[k] = __float2bfloat16(f1);
        }
        *(short8*)(WcombT + (hc * 48 +  0 + hl) * 1280 + kk0) = u5.v;
        *(short8*)(WcombT + (hc * 48 + 16 + hl) * 1280 + kk0) = u3.v;
        *(short8*)(WcombT + (hc * 48 + 32 + hl) * 1280 + kk0) = u1.v;
    } else if (blk < BB * SPAD + 160 + 256) {
        // W01T pack: block = e, threads = h (reads coalesced over h)
        int e = blk - BB * SPAD - 160;
        W01T[t * 256 + e]         = __float2bfloat16(W0[e * HH + t]);
        W01T[(256 + t) * 256 + e] = __float2bfloat16(W1mat[e * HH + t]);
    } else {
        // lengths: b = t>>5, 32 lanes each sum 8 masks, shuffle-reduce
        int b = t >> 5, l = t & 31;
        int ssum = 0;
        #pragma unroll
        for (int k = 0; k < 8; ++k) ssum += masks[b * SS + l * 8 + k];
        #pragma unroll
        for (int o = 16; o; o >>= 1) ssum += __shfl_xor(ssum, o);
        if (l == 0) Linv_buf[b] = (ssum > 0) ? (1.0f / (float)ssum) : 0.0f;
    }
}

// ---- conv as LDS-tiled MFMA GEMM (BM=64, BN=48, BK=128, dbuf) --------------
// Epilogue: tanh+max -> cbf[row][h] (bf16) and cmT[h][row] = c*m*Linv (f32).
__global__ __launch_bounds__(256, 2) void conv_mfma_fused(
        const __hip_bfloat16* __restrict__ xbf,
        const __hip_bfloat16* __restrict__ WcombT,
        const float* __restrict__ cb1, const float* __restrict__ cb3,
        const float* __restrict__ cb5,
        const int* __restrict__ masks, const float* __restrict__ Linv_buf,
        __hip_bfloat16* __restrict__ cbf, float* __restrict__ cmT) {
    __shared__ short8 sA[2][1024];   // [64 rows][16 chunks], 16KB per buf
    __shared__ short8 sB[2][768];    // [48 rows][16 chunks], 12KB per buf

    int blk = blockIdx.x;            // mt*16 + hc
    int mt = blk >> 4, hc = blk & 15;
    int tid = threadIdx.x, w = tid >> 6, lane = tid & 63;
    int fr = lane & 15, fq = lane >> 4;
    int row0 = mt * 64;
    int b = row0 >> 8, s0 = row0 & 255;
    const __hip_bfloat16* xbase = xbf + (b * SPAD + s0) * EMBED;
    const __hip_bfloat16* wbase = WcombT + (hc * 48) * 1280;

    short8 va[4], vb[3];
    auto LOADG = [&](int q) {
        int tap = q >> 1, e0 = (q & 1) * 128;
        const __hip_bfloat16* xs = xbase + tap * EMBED + e0;
        #pragma unroll
        for (int it = 0; it < 4; ++it) {
            int s = tid + it * 256, r = s >> 4, cg = s & 15;
            va[it] = *(const short8*)(xs + r * EMBED + cg * 8);
        }
        const __hip_bfloat16* wsrc = wbase + q * 128;
        #pragma unroll
        for (int it = 0; it < 3; ++it) {
            int s = tid + it * 256, r = s >> 4, cg = s & 15;
            vb[it] = *(const short8*)(wsrc + r * 1280 + cg * 8);
        }
    };
    auto WRITE = [&](int buf) {
        #pragma unroll
        for (int it = 0; it < 4; ++it) {
            int s = tid + it * 256, r = s >> 4, cg = s & 15;
            sA[buf][r * 16 + (cg ^ (r & 15))] = va[it];
        }
        #pragma unroll
        for (int it = 0; it < 3; ++it) {
            int s = tid + it * 256, r = s >> 4, cg = s & 15;
            sB[buf][r * 16 + (cg ^ (r & 15))] = vb[it];
        }
    };

    LOADG(0);
    WRITE(0);
    __syncthreads();

    f32x4 acc0 = {}, acc1 = {}, acc2 = {};
    int ra = w * 16 + fr;            // wave w owns rows w*16..+15
    int cur = 0;
    for (int q = 0; q < 10; ++q) {
        if (q < 9) LOADG(q + 1);
        #pragma unroll
        for (int ks = 0; ks < 4; ++ks) {
            int c = ks * 4 + fq;
            short8 a  = sA[cur][ra * 16 + (c ^ (ra & 15))];
            short8 q0 = sB[cur][fr * 16        + (c ^ fr)];
            short8 q1 = sB[cur][(16 + fr) * 16 + (c ^ fr)];
            short8 q2 = sB[cur][(32 + fr) * 16 + (c ^ fr)];
            acc0 = MFMA16(a, q0, acc0);
            acc1 = MFMA16(a, q1, acc1);
            acc2 = MFMA16(a, q2, acc2);
        }
        if (q < 9) WRITE(cur ^ 1);
        __syncthreads();
        cur ^= 1;
    }

    int h = hc * 16 + fr;
    float bb5 = cb5[h], bb3 = cb3[h], bb1 = cb1[h];
    float Linv = Linv_buf[b];
    #pragma unroll
    for (int j = 0; j < 4; ++j) {
        int row = row0 + w * 16 + fq * 4 + j;
        float t5 = fast_tanh(acc0[j] + bb5);
        float t3 = fast_tanh(acc1[j] + bb3);
        float t1 = fast_tanh(acc2[j] + bb1);
        float v = fmaxf(t1, fmaxf(t3, t5));
        cbf[row * HH + h] = __float2bfloat16(v);
        cmT[h * NROWS + row] = v * (float)masks[row] * Linv;
    }
}

// ---- g0/g1 GEMM; full register prefetch; E=exp2(-log2e*(v+bias)) -----------
// Outputs TRANSPOSED [h][row] via LDS transpose (coalesced 32B stores).
__global__ __launch_bounds__(256) void gemm_g_mfma_kernel(
        const __hip_bfloat16* __restrict__ cbf,
        const __hip_bfloat16* __restrict__ W01T,
        const float* __restrict__ b0, const float* __restrict__ b1v,
        float* __restrict__ E0T, float* __restrict__ E1T) {
    __shared__ float s_out[64][33];  // [colLocal][rowLocal], padded

    int blk = blockIdx.x;            // 64 m-tiles * 8 n-tiles = 512
    int by = blk >> 3, bx = blk & 7;
    int tid = threadIdx.x;
    int w = tid >> 6, lane = tid & 63;
    int wr = w >> 1, wc = w & 1;
    int m0 = by * 32 + wr * 16;
    int n0 = bx * 64 + wc * 32;
    int fr = lane & 15, fq = lane >> 4;

    const short8* ap  = (const short8*)(cbf + (m0 + fr) * HH + fq * 8);
    const short8* bp0 = (const short8*)(W01T + (n0 + fr) * HH + fq * 8);
    const short8* bp1 = (const short8*)(W01T + (n0 + 16 + fr) * HH + fq * 8);

    short8 af[8], bf0[8], bf1[8];    // all 24 loads issued up front
    #pragma unroll
    for (int ks = 0; ks < 8; ++ks) af[ks] = ap[ks * 4];
    #pragma unroll
    for (int ks = 0; ks < 8; ++ks) { bf0[ks] = bp0[ks * 4]; bf1[ks] = bp1[ks * 4]; }

    f32x4 acc[2] = {};
    #pragma unroll
    for (int ks = 0; ks < 8; ++ks) {
        acc[0] = MFMA16(af[ks], bf0[ks], acc[0]);
        acc[1] = MFMA16(af[ks], bf1[ks], acc[1]);
    }
    #pragma unroll
    for (int n = 0; n < 2; ++n) {
        int col = n0 + n * 16 + fr;
        float bias = (col < 256) ? b0[col] : b1v[col - 256];
        int cl = wc * 32 + n * 16 + fr;
        #pragma unroll
        for (int j = 0; j < 4; ++j) {
            int rl = wr * 16 + fq * 4 + j;
            s_out[cl][rl] = fast_exp2(NLOG2E * (acc[n][j] + bias));
        }
    }
    __syncthreads();
    {
        float* dstbase = (bx < 4) ? (E0T + (bx * 64) * NROWS)
                                  : (E1T + (bx * 64 - 256) * NROWS);
        int cl = tid >> 2, rq = tid & 3;   // 64 cols x 4 row-octets
        f32x4 o0, o1;
        #pragma unroll
        for (int k = 0; k < 4; ++k) { o0[k] = s_out[cl][rq * 8 + k];
                                      o1[k] = s_out[cl][rq * 8 + 4 + k]; }
        float* dst = dstbase + cl * NROWS + by * 32 + rq * 8;
        *(f32x4*)dst = o0;
        *(f32x4*)(dst + 4) = o1;
    }
}

// ---- relation: block=(b, h-pair); threads=i; LDS j-loop --------------------
// One f32x4 ds_read per j serves TWO h-outputs; staging amortized 2x.
__global__ __launch_bounds__(256) void relation_kernel(
        const float* __restrict__ E0T, const float* __restrict__ E1T,
        const float* __restrict__ cmT, const int* __restrict__ masks,
        float* __restrict__ relT) {
    int blk = blockIdx.x;            // b*128 + hp
    int b = blk >> 7, hp = blk & 127;
    int i = threadIdx.x;
    int row = b * SS + i;
    int h0 = hp * 2;

    __shared__ f32x4 ps[SS];         // {e1[h0], cm[h0], e1[h1], cm[h1]} per j
    {
        f32x4 pv;
        pv[0] = E1T[(h0    ) * NROWS + row];   // coalesced
        pv[1] = cmT[(h0    ) * NROWS + row];   // coalesced
        pv[2] = E1T[(h0 + 1) * NROWS + row];   // coalesced
        pv[3] = cmT[(h0 + 1) * NROWS + row];   // coalesced
        ps[i] = pv;
    }
    __syncthreads();

    float e0a = E0T[(h0    ) * NROWS + row];   // coalesced
    float e0b = E0T[(h0 + 1) * NROWS + row];   // coalesced
    float acca = 0.f, accb = 0.f;
    #pragma unroll 8
    for (int j = 0; j < SS; ++j) {
        f32x4 v = ps[j];                       // uniform -> LDS broadcast
        acca = fmaf(fast_rcp(fmaf(e0a, v[0], 1.0f)), v[1], acca);
        accb = fmaf(fast_rcp(fmaf(e0b, v[2], 1.0f)), v[3], accb);
    }
    float mi = (float)masks[row];
    relT[(h0    ) * NROWS + row] = fast_tanh(acca * mi);   // coalesced
    relT[(h0 + 1) * NROWS + row] = fast_tanh(accb * mi);   // coalesced
}

// ---- final: coalesced relT reads, Wo in LDS, partial-reduce, softmax -------
// block = (b, 32 i's); threads = 8 h-groups x 32 i.
__global__ __launch_bounds__(256) void final_kernel(
        const float* __restrict__ relT,
        const float* __restrict__ Wo, const float* __restrict__ bo,
        float* __restrict__ out) {
    int blk = blockIdx.x;            // b*8 + iblk
    int b = blk >> 3, iblk = blk & 7;
    int tid = threadIdx.x;
    int hg = tid >> 5, il = tid & 31;
    int row = b * SS + iblk * 32 + il;

    __shared__ float wo_s[HH * NTAGS];       // 17.0 KB
    __shared__ float part[8][32][NTAGS];     // 17.4 KB

    for (int idx = tid; idx < HH * NTAGS; idx += 256) wo_s[idx] = Wo[idx];
    __syncthreads();

    float acc[NTAGS];
    #pragma unroll
    for (int t = 0; t < NTAGS; ++t) acc[t] = 0.f;
    const float* rbase = relT + row;
    for (int k = 0; k < 32; ++k) {
        int hh = hg * 32 + k;
        float v = rbase[hh * NROWS];         // 128B coalesced per 32 lanes
        const float* wrow = wo_s + hh * NTAGS;
        #pragma unroll
        for (int t = 0; t < NTAGS; ++t) acc[t] = fmaf(v, wrow[t], acc[t]);
    }
    #pragma unroll
    for (int t = 0; t < NTAGS; ++t) part[hg][il][t] = acc[t];
    __syncthreads();

    for (int idx = tid; idx < 32 * NTAGS; idx += 256) {
        int ii = idx / NTAGS, t = idx - ii * NTAGS;
        float s = bo[t];
        #pragma unroll
        for (int g = 0; g < 8; ++g) s += part[g][ii][t];
        part[0][ii][t] = s;
    }
    __syncthreads();

    if (tid < 32) {
        float mx = -1e30f;
        #pragma unroll
        for (int t = 0; t < NTAGS; ++t) mx = fmaxf(mx, part[0][tid][t]);
        float ex[NTAGS], sum = 0.f;
        #pragma unroll
        for (int t = 0; t < NTAGS; ++t) { ex[t] = __expf(part[0][tid][t] - mx); sum += ex[t]; }
        float si = fast_rcp(sum);
        int orow = b * SS + iblk * 32 + tid;
        #pragma unroll
        for (int t = 0; t < NTAGS; ++t)
            out[orow * NTAGS + t] = ex[t] * si;
    }
}

extern "C" void kernel_launch(void* const* d_in, const int* in_sizes, int n_in,
                              void* d_out, int out_size, void* d_ws, size_t ws_size,
                              hipStream_t stream) {
    const int*   tokens     = (const int*)d_in[0];
    const int*   masks      = (const int*)d_in[1];
    const float* char_emb   = (const float*)d_in[2];
    const float* bigram_emb = (const float*)d_in[3];
    const float* conv1_w    = (const float*)d_in[4];
    const float* conv1_b    = (const float*)d_in[5];
    const float* conv3_w    = (const float*)d_in[6];
    const float* conv3_b    = (const float*)d_in[7];
    const float* conv5_w    = (const float*)d_in[8];
    const float* conv5_b    = (const float*)d_in[9];
    const float* W0         = (const float*)d_in[10];
    const float* b0         = (const float*)d_in[11];
    const float* W1         = (const float*)d_in[12];
    const float* b1         = (const float*)d_in[13];
    const float* Wo         = (const float*)d_in[14];
    const float* bo         = (const float*)d_in[15];
    float* out = (float*)d_out;

    char* p = (char*)d_ws;
    __hip_bfloat16* xbf    = (__hip_bfloat16*)p;  p += BB * SPAD * EMBED * 2;   // 1.06 MB
    __hip_bfloat16* WcombT = (__hip_bfloat16*)p;  p += 768 * 1280 * 2;          // 1.97 MB
    __hip_bfloat16* W01T   = (__hip_bfloat16*)p;  p += 512 * 256 * 2;           // 0.26 MB
    __hip_bfloat16* cbf    = (__hip_bfloat16*)p;  p += NROWS * HH * 2;          // 1.05 MB
    float* cmT  = (float*)p;  p += (size_t)HH * NROWS * 4;                      // 2.1 MB
    float* E0T  = (float*)p;  p += (size_t)HH * NROWS * 4;                      // 2.1 MB
    float* E1T  = (float*)p;  p += (size_t)HH * NROWS * 4;                      // 2.1 MB
    float* relT = (float*)p;  p += (size_t)HH * NROWS * 4;                      // 2.1 MB
    float* Linv_buf = (float*)p;  p += 64;

    embed_pack_kernel<<<BB * SPAD + 160 + 256 + 1, 256, 0, stream>>>(
        tokens, char_emb, bigram_emb, conv1_w, conv3_w, conv5_w, W0, W1,
        masks, xbf, WcombT, W01T, Linv_buf);
    conv_mfma_fused<<<512, 256, 0, stream>>>(xbf, WcombT, conv1_b, conv3_b,
                                             conv5_b, masks, Linv_buf, cbf, cmT);
    gemm_g_mfma_kernel<<<512, 256, 0, stream>>>(cbf, W01T, b0, b1, E0T, E1T);
    relation_kernel<<<BB * 128, 256, 0, stream>>>(E0T, E1T, cmT, masks, relT);
    final_kernel<<<BB * 8, 256, 0, stream>>>(relT, Wo, bo, out);
}